// Round 7
// baseline (82.595 us; speedup 1.0000x reference)
//
#include <hip/hip_runtime.h>

namespace {

constexpr int NB = 4;
constexpr int ND = 128;
constexpr int NH = 192;
constexpr int NW = 192;
constexpr int CD = 16;    // output planes per block; 128/16 = 8 exact
constexpr int LDSW = 194; // 1 left pad + 192 + 1 right pad

__global__ __launch_bounds__(256, 2)
void edge_loss3d(const float* __restrict__ pred,
                 const float* __restrict__ targ,
                 float* __restrict__ out)
{
    const int lane = threadIdx.x & 63;
    const int wid  = threadIdx.x >> 6;
    const int d0   = blockIdx.x * CD;
    const int h0   = blockIdx.y * 4;          // block's 4 output rows h0..h0+3
    const int b    = blockIdx.z;

    const long long PL = (long long)NH * NW;

    __shared__ float lds[2][2][6][LDSW];      // [buf][tensor][staged row][w]
    __shared__ float wsum[4];

    // zero the w-pads of both buffers once (first use is after phase-0 barrier)
    if (threadIdx.x < 48) {
        const int bf = threadIdx.x / 24;
        const int t  = (threadIdx.x / 12) & 1;
        const int r  = (threadIdx.x % 12) / 2;
        const int s  = threadIdx.x & 1;
        lds[bf][t][r][s * (LDSW - 1)] = 0.f;
    }

    // staging role: wave stages tensor tw, staged rows rbase..rbase+2 (idx 0 <-> h0-1)
    const int tw = wid >> 1;
    const int rbase = (wid & 1) * 3;
    const float* sb = (tw ? targ : pred) + (long long)b * ND * PL + 3 * lane;

    // per-staged-row offsets (clamped) and validity masks — constant over planes
    const int hh0 = h0 - 1 + rbase, hh1 = hh0 + 1, hh2 = hh0 + 2;
    const int ro0 = (hh0 < 0 ? 0 : (hh0 > NH - 1 ? NH - 1 : hh0)) * NW;
    const int ro1 = (hh1 < 0 ? 0 : (hh1 > NH - 1 ? NH - 1 : hh1)) * NW;
    const int ro2 = (hh2 < 0 ? 0 : (hh2 > NH - 1 ? NH - 1 : hh2)) * NW;
    const float rm0 = (hh0 >= 0 && hh0 < NH) ? 1.f : 0.f;
    const float rm1 = (hh1 >= 0 && hh1 < NH) ? 1.f : 0.f;
    const float rm2 = (hh2 >= 0 && hh2 < NH) ? 1.f : 0.f;

    float* ldw0 = &lds[0][tw][rbase][1 + 3 * lane];
    float* ldw1 = &lds[1][tw][rbase][1 + 3 * lane];
    const float* ldr00 = &lds[0][0][wid][1 + 3 * lane];  // buf0, pred
    const float* ldr01 = &lds[0][1][wid][1 + 3 * lane];  // buf0, targ
    const float* ldr10 = &lds[1][0][wid][1 + 3 * lane];  // buf1, pred
    const float* ldr11 = &lds[1][1][wid][1 + 3 * lane];  // buf1, targ

    // in-flight staged rows (9 scalars) and rolling state q (literal indices only)
    float g00, g01, g02, g10, g11, g12, g20, g21, g22;
    float q[2][3][3][3];
    float acc = 0.f;

#define PREFETCH(P) do {                                                      \
    const int pc_ = (P) < 0 ? 0 : ((P) > ND - 1 ? ND - 1 : (P));              \
    const float* sp_ = sb + (long long)pc_ * PL;                              \
    const float pm_ = ((P) >= 0 && (P) < ND) ? 1.f : 0.f;                     \
    const float m0_ = pm_ * rm0, m1_ = pm_ * rm1, m2_ = pm_ * rm2;            \
    g00 = sp_[ro0 + 0] * m0_; g01 = sp_[ro0 + 1] * m0_; g02 = sp_[ro0 + 2] * m0_; \
    g10 = sp_[ro1 + 0] * m1_; g11 = sp_[ro1 + 1] * m1_; g12 = sp_[ro1 + 2] * m1_; \
    g20 = sp_[ro2 + 0] * m2_; g21 = sp_[ro2 + 1] * m2_; g22 = sp_[ro2 + 2] * m2_; \
} while (0)

#define STAGE_WRITE(BUF) do {                                                 \
    float* w_ = (BUF) ? ldw1 : ldw0;                                          \
    w_[0] = g00; w_[1] = g01; w_[2] = g02;                                    \
    w_[LDSW + 0] = g10; w_[LDSW + 1] = g11; w_[LDSW + 2] = g12;               \
    w_[2 * LDSW + 0] = g20; w_[2 * LDSW + 1] = g21; w_[2 * LDSW + 2] = g22;   \
} while (0)

// one h-row pass of tensor T from buffer BUF into slot SP (all literals)
#define ROWPASS(T, SP, RR, BUF) do {                                          \
    const float* rp_ = ((BUF) ? ((T) ? ldr11 : ldr10)                         \
                              : ((T) ? ldr01 : ldr00)) + (RR) * LDSW;         \
    const float xm_ = rp_[-1], x0_ = rp_[0], x1_ = rp_[1], x2_ = rp_[2], xp_ = rp_[3]; \
    const float s0_ = fmaf(2.f, x0_, xm_ + x1_) * 0.25f;                      \
    const float s1_ = fmaf(2.f, x1_, x0_ + x2_) * 0.25f;                      \
    const float s2_ = fmaf(2.f, x2_, x1_ + xp_) * 0.25f;                      \
    const float t0_ = x1_ - xm_, t1_ = x2_ - x0_, t2_ = xp_ - x1_;            \
    if ((RR) == 0) {                                                          \
        q[T][SP][0][0] = 0.25f*s0_; q[T][SP][0][1] = 0.25f*s1_; q[T][SP][0][2] = 0.25f*s2_; \
        q[T][SP][1][0] = -s0_;      q[T][SP][1][1] = -s1_;      q[T][SP][1][2] = -s2_;      \
        q[T][SP][2][0] = 0.25f*t0_; q[T][SP][2][1] = 0.25f*t1_; q[T][SP][2][2] = 0.25f*t2_; \
    } else if ((RR) == 1) {                                                   \
        q[T][SP][0][0] = fmaf(0.5f, s0_, q[T][SP][0][0]);                     \
        q[T][SP][0][1] = fmaf(0.5f, s1_, q[T][SP][0][1]);                     \
        q[T][SP][0][2] = fmaf(0.5f, s2_, q[T][SP][0][2]);                     \
        /* sobel_h center weight = 0 -> ts unchanged */                       \
        q[T][SP][2][0] = fmaf(0.5f, t0_, q[T][SP][2][0]);                     \
        q[T][SP][2][1] = fmaf(0.5f, t1_, q[T][SP][2][1]);                     \
        q[T][SP][2][2] = fmaf(0.5f, t2_, q[T][SP][2][2]);                     \
    } else {                                                                  \
        q[T][SP][0][0] = fmaf(0.25f, s0_, q[T][SP][0][0]);                    \
        q[T][SP][0][1] = fmaf(0.25f, s1_, q[T][SP][0][1]);                    \
        q[T][SP][0][2] = fmaf(0.25f, s2_, q[T][SP][0][2]);                    \
        q[T][SP][1][0] += s0_; q[T][SP][1][1] += s1_; q[T][SP][1][2] += s2_;  \
        q[T][SP][2][0] = fmaf(0.25f, t0_, q[T][SP][2][0]);                    \
        q[T][SP][2][1] = fmaf(0.25f, t1_, q[T][SP][2][1]);                    \
        q[T][SP][2][2] = fmaf(0.25f, t2_, q[T][SP][2][2]);                    \
    }                                                                         \
} while (0)

// phase k: write staged plane into BUF, prefetch PNEXT, one barrier, compute
#define PHASE(SP, BUF, PNEXT) do {                                            \
    STAGE_WRITE(BUF);                                                         \
    PREFETCH(PNEXT);                                                          \
    __syncthreads();                                                          \
    ROWPASS(0, SP, 0, BUF); ROWPASS(0, SP, 1, BUF); ROWPASS(0, SP, 2, BUF);   \
    ROWPASS(1, SP, 0, BUF); ROWPASS(1, SP, 1, BUF); ROWPASS(1, SP, 2, BUF);   \
} while (0)

#define EDGE(T, J, SM, SC, SP, EVAR) do {                                     \
    const float gx_ = fmaf(2.f, q[T][SC][2][J], q[T][SM][2][J] + q[T][SP][2][J]) * 0.25f; \
    const float gy_ = fmaf(2.f, q[T][SC][1][J], q[T][SM][1][J] + q[T][SP][1][J]) * 0.25f; \
    const float gz_ = q[T][SP][0][J] - q[T][SM][0][J];                        \
    EVAR = sqrtf(fmaf(gx_, gx_, fmaf(gy_, gy_, fmaf(gz_, gz_, 1e-8f))));      \
} while (0)

#define EMIT(SM, SC, SP) do {                                                 \
    float e0_, e1_;                                                           \
    EDGE(0, 0, SM, SC, SP, e0_); EDGE(1, 0, SM, SC, SP, e1_); acc += fabsf(e0_ - e1_); \
    EDGE(0, 1, SM, SC, SP, e0_); EDGE(1, 1, SM, SC, SP, e1_); acc += fabsf(e0_ - e1_); \
    EDGE(0, 2, SM, SC, SP, e0_); EDGE(1, 2, SM, SC, SP, e1_); acc += fabsf(e0_ - e1_); \
} while (0)

    // 18 phases: plane P_k = d0-1+k, slot = k%3, buf = k%2; emit from k>=2.
    PREFETCH(d0 - 1);
    // group 0 (k=0..5), planes d0-1 .. d0+4
    PHASE(0, 0, d0);                          // k=0
    PHASE(1, 1, d0 + 1);                      // k=1
    PHASE(2, 0, d0 + 2); EMIT(0, 1, 2);       // k=2  -> output d0
    PHASE(0, 1, d0 + 3); EMIT(1, 2, 0);       // k=3
    PHASE(1, 0, d0 + 4); EMIT(2, 0, 1);       // k=4
    PHASE(2, 1, d0 + 5); EMIT(0, 1, 2);       // k=5
    // groups 1..2 (k=6..17), planes d0+5 .. d0+16
    for (int g = 1; g <= 2; ++g) {
        const int pb = d0 - 1 + 6 * g;        // plane of this group's first phase
        PHASE(0, 0, pb + 1); EMIT(1, 2, 0);
        PHASE(1, 1, pb + 2); EMIT(2, 0, 1);
        PHASE(2, 0, pb + 3); EMIT(0, 1, 2);
        PHASE(0, 1, pb + 4); EMIT(1, 2, 0);
        PHASE(1, 0, pb + 5); EMIT(2, 0, 1);
        PHASE(2, 1, pb + 6); EMIT(0, 1, 2);   // final prefetch is dead -> DCE'd
    }

#undef PREFETCH
#undef STAGE_WRITE
#undef ROWPASS
#undef PHASE
#undef EDGE
#undef EMIT

    // wave reduce -> block reduce -> one atomic per block
    #pragma unroll
    for (int off = 32; off > 0; off >>= 1)
        acc += __shfl_down(acc, off, 64);
    if (lane == 0) wsum[wid] = acc;
    __syncthreads();
    if (threadIdx.x == 0) {
        const float invN = 1.f / (float)((long long)NB * ND * NH * NW);
        atomicAdd(out, (wsum[0] + wsum[1] + wsum[2] + wsum[3]) * invN);
    }
}

} // namespace

extern "C" void kernel_launch(void* const* d_in, const int* in_sizes, int n_in,
                              void* d_out, int out_size, void* d_ws, size_t ws_size,
                              hipStream_t stream) {
    const float* pred = (const float*)d_in[0];
    const float* targ = (const float*)d_in[1];
    float* out = (float*)d_out;
    (void)in_sizes; (void)n_in; (void)out_size; (void)d_ws; (void)ws_size;

    hipMemsetAsync(out, 0, sizeof(float), stream);

    dim3 grid(ND / CD, NH / 4, NB);   // (8, 48, 4) = 1536 blocks, 6/CU
    dim3 block(256);
    edge_loss3d<<<grid, block, 0, stream>>>(pred, targ, out);
}

// Round 8
// 69.155 us; speedup vs baseline: 1.1943x; 1.1943x over previous
//
#include <hip/hip_runtime.h>

namespace {

constexpr int NB = 4;
constexpr int ND = 128;
constexpr int NH = 192;
constexpr int NW = 192;
constexpr int CD = 16;    // output planes per block; 128/16 = 8 exact
constexpr int LDSW = 194; // 1 left pad + 192 + 1 right pad

__global__ __launch_bounds__(256, 2)
void edge_loss3d(const float* __restrict__ pred,
                 const float* __restrict__ targ,
                 float* __restrict__ out)
{
    const int lane = threadIdx.x & 63;
    const int wid  = threadIdx.x >> 6;
    const int d0   = blockIdx.x * CD;
    const int h0   = blockIdx.y * 4;          // block's 4 output rows h0..h0+3
    const int b    = blockIdx.z;

    const long long PL = (long long)NH * NW;

    __shared__ float lds[2][6][LDSW];
    __shared__ float wsum[4];

    // zero the w-pads once (visible after the first PROCESS's barriers)
    if (threadIdx.x < 24) {
        const int t = threadIdx.x / 12, r = (threadIdx.x % 12) / 2, s = threadIdx.x & 1;
        lds[t][r][s * (LDSW - 1)] = 0.f;
    }

    // staging role: wave stages tensor tw, staged rows rbase..rbase+2 (idx 0 <-> h0-1)
    const int tw = wid >> 1;
    const int rbase = (wid & 1) * 3;
    const float* sb = (tw ? targ : pred) + (long long)b * ND * PL + 3 * lane;

    // per-staged-row offsets (clamped) and validity masks — constant over planes
    const int hh0 = h0 - 1 + rbase, hh1 = hh0 + 1, hh2 = hh0 + 2;
    const int ro0 = (hh0 < 0 ? 0 : (hh0 > NH - 1 ? NH - 1 : hh0)) * NW;
    const int ro1 = (hh1 < 0 ? 0 : (hh1 > NH - 1 ? NH - 1 : hh1)) * NW;
    const int ro2 = (hh2 < 0 ? 0 : (hh2 > NH - 1 ? NH - 1 : hh2)) * NW;
    const float rm0 = (hh0 >= 0 && hh0 < NH) ? 1.f : 0.f;
    const float rm1 = (hh1 >= 0 && hh1 < NH) ? 1.f : 0.f;
    const float rm2 = (hh2 >= 0 && hh2 < NH) ? 1.f : 0.f;

    float* ldw = &lds[tw][rbase][1 + 3 * lane];
    const float* ldr0 = &lds[0][wid][1 + 3 * lane];
    const float* ldr1 = &lds[1][wid][1 + 3 * lane];

    // in-flight staged rows (9 scalars) and rolling state q (literal indices only)
    float g00, g01, g02, g10, g11, g12, g20, g21, g22;
    float q[2][3][3][3];
    float acc = 0.f;

#define PREFETCH(P) do {                                                      \
    const int pc_ = (P) < 0 ? 0 : ((P) > ND - 1 ? ND - 1 : (P));              \
    const float* sp_ = sb + (long long)pc_ * PL;                              \
    const float pm_ = ((P) >= 0 && (P) < ND) ? 1.f : 0.f;                     \
    const float m0_ = pm_ * rm0, m1_ = pm_ * rm1, m2_ = pm_ * rm2;            \
    g00 = sp_[ro0 + 0] * m0_; g01 = sp_[ro0 + 1] * m0_; g02 = sp_[ro0 + 2] * m0_; \
    g10 = sp_[ro1 + 0] * m1_; g11 = sp_[ro1 + 1] * m1_; g12 = sp_[ro1 + 2] * m1_; \
    g20 = sp_[ro2 + 0] * m2_; g21 = sp_[ro2 + 1] * m2_; g22 = sp_[ro2 + 2] * m2_; \
} while (0)

#define STAGE_WRITE() do {                                                    \
    ldw[0] = g00; ldw[1] = g01; ldw[2] = g02;                                 \
    ldw[LDSW + 0] = g10; ldw[LDSW + 1] = g11; ldw[LDSW + 2] = g12;            \
    ldw[2 * LDSW + 0] = g20; ldw[2 * LDSW + 1] = g21; ldw[2 * LDSW + 2] = g22;\
} while (0)

// one h-row pass of tensor T into slot SP; reads staged row (wid+RR) from LDS
#define ROWPASS(T, SP, RR) do {                                               \
    const float* rp_ = (T ? ldr1 : ldr0) + (RR) * LDSW;                       \
    const float xm_ = rp_[-1], x0_ = rp_[0], x1_ = rp_[1], x2_ = rp_[2], xp_ = rp_[3]; \
    const float s0_ = fmaf(2.f, x0_, xm_ + x1_) * 0.25f;                      \
    const float s1_ = fmaf(2.f, x1_, x0_ + x2_) * 0.25f;                      \
    const float s2_ = fmaf(2.f, x2_, x1_ + xp_) * 0.25f;                      \
    const float t0_ = x1_ - xm_, t1_ = x2_ - x0_, t2_ = xp_ - x1_;            \
    if ((RR) == 0) {                                                          \
        q[T][SP][0][0] = 0.25f*s0_; q[T][SP][0][1] = 0.25f*s1_; q[T][SP][0][2] = 0.25f*s2_; \
        q[T][SP][1][0] = -s0_;      q[T][SP][1][1] = -s1_;      q[T][SP][1][2] = -s2_;      \
        q[T][SP][2][0] = 0.25f*t0_; q[T][SP][2][1] = 0.25f*t1_; q[T][SP][2][2] = 0.25f*t2_; \
    } else if ((RR) == 1) {                                                   \
        q[T][SP][0][0] = fmaf(0.5f, s0_, q[T][SP][0][0]);                     \
        q[T][SP][0][1] = fmaf(0.5f, s1_, q[T][SP][0][1]);                     \
        q[T][SP][0][2] = fmaf(0.5f, s2_, q[T][SP][0][2]);                     \
        /* sobel_h center weight = 0 -> ts unchanged */                       \
        q[T][SP][2][0] = fmaf(0.5f, t0_, q[T][SP][2][0]);                     \
        q[T][SP][2][1] = fmaf(0.5f, t1_, q[T][SP][2][1]);                     \
        q[T][SP][2][2] = fmaf(0.5f, t2_, q[T][SP][2][2]);                     \
    } else {                                                                  \
        q[T][SP][0][0] = fmaf(0.25f, s0_, q[T][SP][0][0]);                    \
        q[T][SP][0][1] = fmaf(0.25f, s1_, q[T][SP][0][1]);                    \
        q[T][SP][0][2] = fmaf(0.25f, s2_, q[T][SP][0][2]);                    \
        q[T][SP][1][0] += s0_; q[T][SP][1][1] += s1_; q[T][SP][1][2] += s2_;  \
        q[T][SP][2][0] = fmaf(0.25f, t0_, q[T][SP][2][0]);                    \
        q[T][SP][2][1] = fmaf(0.25f, t1_, q[T][SP][2][1]);                    \
        q[T][SP][2][2] = fmaf(0.25f, t2_, q[T][SP][2][2]);                    \
    }                                                                         \
} while (0)

// write staged plane to LDS, prefetch plane PNEXT, compute staged plane into slot SP
#define PROCESS(SP, PNEXT) do {                                               \
    __syncthreads();                                                          \
    STAGE_WRITE();                                                            \
    __syncthreads();                                                          \
    PREFETCH(PNEXT);                                                          \
    ROWPASS(0, SP, 0); ROWPASS(0, SP, 1); ROWPASS(0, SP, 2);                  \
    ROWPASS(1, SP, 0); ROWPASS(1, SP, 1); ROWPASS(1, SP, 2);                  \
} while (0)

#define PROCESS_LAST(SP) do {                                                 \
    __syncthreads();                                                          \
    STAGE_WRITE();                                                            \
    __syncthreads();                                                          \
    ROWPASS(0, SP, 0); ROWPASS(0, SP, 1); ROWPASS(0, SP, 2);                  \
    ROWPASS(1, SP, 0); ROWPASS(1, SP, 1); ROWPASS(1, SP, 2);                  \
} while (0)

#define EDGE(T, J, SM, SC, SP, EVAR) do {                                     \
    const float gx_ = fmaf(2.f, q[T][SC][2][J], q[T][SM][2][J] + q[T][SP][2][J]) * 0.25f; \
    const float gy_ = fmaf(2.f, q[T][SC][1][J], q[T][SM][1][J] + q[T][SP][1][J]) * 0.25f; \
    const float gz_ = q[T][SP][0][J] - q[T][SM][0][J];                        \
    EVAR = sqrtf(fmaf(gx_, gx_, fmaf(gy_, gy_, fmaf(gz_, gz_, 1e-8f))));      \
} while (0)

#define EMIT(SM, SC, SP) do {                                                 \
    float e0_, e1_;                                                           \
    EDGE(0, 0, SM, SC, SP, e0_); EDGE(1, 0, SM, SC, SP, e1_); acc += fabsf(e0_ - e1_); \
    EDGE(0, 1, SM, SC, SP, e0_); EDGE(1, 1, SM, SC, SP, e1_); acc += fabsf(e0_ - e1_); \
    EDGE(0, 2, SM, SC, SP, e0_); EDGE(1, 2, SM, SC, SP, e1_); acc += fabsf(e0_ - e1_); \
} while (0)

    // prologue: plane d0-1 -> slot 0, plane d0 -> slot 1
    PREFETCH(d0 - 1);
    PROCESS(0, d0);          // computes plane d0-1
    PROCESS(1, d0 + 1);      // computes plane d0

    // steady state: 5 groups x 3 phases; computed planes d0+1 .. d0+15
    for (int gg = 0; gg < 5; ++gg) {
        const int p = d0 + 1 + gg * 3;
        PROCESS(2, p + 1); EMIT(0, 1, 2);   // emit output plane d0+3*gg
        PROCESS(0, p + 2); EMIT(1, 2, 0);
        PROCESS(1, p + 3); EMIT(2, 0, 1);
    }
    // epilogue: compute plane d0+16 (masked out for last block), emit d0+15
    PROCESS_LAST(2);
    EMIT(0, 1, 2);

#undef PREFETCH
#undef STAGE_WRITE
#undef ROWPASS
#undef PROCESS
#undef PROCESS_LAST
#undef EDGE
#undef EMIT

    // wave reduce -> block reduce -> one atomic per block
    #pragma unroll
    for (int off = 32; off > 0; off >>= 1)
        acc += __shfl_down(acc, off, 64);
    if (lane == 0) wsum[wid] = acc;
    __syncthreads();
    if (threadIdx.x == 0) {
        const float invN = 1.f / (float)((long long)NB * ND * NH * NW);
        atomicAdd(out, (wsum[0] + wsum[1] + wsum[2] + wsum[3]) * invN);
    }
}

} // namespace

extern "C" void kernel_launch(void* const* d_in, const int* in_sizes, int n_in,
                              void* d_out, int out_size, void* d_ws, size_t ws_size,
                              hipStream_t stream) {
    const float* pred = (const float*)d_in[0];
    const float* targ = (const float*)d_in[1];
    float* out = (float*)d_out;
    (void)in_sizes; (void)n_in; (void)out_size; (void)d_ws; (void)ws_size;

    hipMemsetAsync(out, 0, sizeof(float), stream);

    dim3 grid(ND / CD, NH / 4, NB);   // (8, 48, 4) = 1536 blocks, 6/CU
    dim3 block(256);
    edge_loss3d<<<grid, block, 0, stream>>>(pred, targ, out);
}

// Round 9
// 65.339 us; speedup vs baseline: 1.2641x; 1.0584x over previous
//
#include <hip/hip_runtime.h>

namespace {

typedef float v2f __attribute__((ext_vector_type(2)));

__device__ __forceinline__ v2f mk2(float a, float b) { v2f r; r.x = a; r.y = b; return r; }

constexpr int NB = 4;
constexpr int ND = 128;
constexpr int NH = 192;
constexpr int NW = 192;
constexpr int PLI = NH * NW;
constexpr int CD = 16;    // output planes per block; 128/16 = 8 exact
constexpr int LDSW = 194; // 1 left pad + 192 + 1 right pad

__global__ __launch_bounds__(256, 2)
void edge_loss3d(const float* __restrict__ pred,
                 const float* __restrict__ targ,
                 float* __restrict__ out)
{
    const int lane = threadIdx.x & 63;
    const int wid  = threadIdx.x >> 6;
    const int d0   = blockIdx.x * CD;
    const int h0   = blockIdx.y * 4;          // block's 4 output rows h0..h0+3
    const int b    = blockIdx.z;

    __shared__ float lds[2][6][LDSW];
    __shared__ float zrow[LDSW];
    __shared__ float wsum[4];

    // zero pads + zero-row once (first read is after PROCESS barriers)
    if (threadIdx.x < LDSW) zrow[threadIdx.x] = 0.f;
    if (threadIdx.x < 24) {
        const int t = threadIdx.x / 12, r = (threadIdx.x % 12) / 2, s = threadIdx.x & 1;
        lds[t][r][s * (LDSW - 1)] = 0.f;
    }

    // staging role: wave stages tensor tw, staged rows rbase..rbase+2 (idx 0 <-> h0-1)
    const int tw = wid >> 1;
    const int rbase = (wid & 1) * 3;
    const float* sb = (tw ? targ : pred) + (size_t)b * ND * PLI + 3 * lane;

    // clamped row offsets for staging loads (garbage rows are never read back)
    const int hh0 = h0 - 1 + rbase, hh1 = hh0 + 1, hh2 = hh0 + 2;
    const int ro0 = (hh0 < 0 ? 0 : (hh0 > NH - 1 ? NH - 1 : hh0)) * NW;
    const int ro1 = (hh1 < 0 ? 0 : (hh1 > NH - 1 ? NH - 1 : hh1)) * NW;
    const int ro2 = (hh2 < 0 ? 0 : (hh2 > NH - 1 ? NH - 1 : hh2)) * NW;

    float* ldw = &lds[tw][rbase][1 + 3 * lane];

    // read pointers with zero-row redirect (h-boundary handled here, no masks)
    const bool vlo = (h0 + wid - 1) >= 0;
    const bool vhi = (h0 + wid + 1) < NH;
    const float* zz   = &zrow[1 + 3 * lane];
    const float* ldp0 = vlo ? &lds[0][wid][1 + 3 * lane]     : zz;
    const float* ldp1 =       &lds[0][wid + 1][1 + 3 * lane];
    const float* ldp2 = vhi ? &lds[0][wid + 2][1 + 3 * lane] : zz;
    const float* ldt0 = vlo ? &lds[1][wid][1 + 3 * lane]     : zz;
    const float* ldt1 =       &lds[1][wid + 1][1 + 3 * lane];
    const float* ldt2 = vhi ? &lds[1][wid + 2][1 + 3 * lane] : zz;

    // in-flight staged rows + rolling state (pairs + scalar), literal indices only
    float g00, g01, g02, g10, g11, g12, g20, g21, g22;
    v2f   qa[2][3][3];
    float qc[2][3][3];
    v2f   accA = mk2(0.f, 0.f);
    float acc2 = 0.f;

#define RPTR(T, RR) ((T) ? ((RR) == 0 ? ldt0 : (RR) == 1 ? ldt1 : ldt2)       \
                         : ((RR) == 0 ? ldp0 : (RR) == 1 ? ldp1 : ldp2))

#define PREFETCH(P) do {                                                      \
    const int o_ = (P) * PLI;                                                 \
    g00 = sb[o_ + ro0]; g01 = sb[o_ + ro0 + 1]; g02 = sb[o_ + ro0 + 2];       \
    g10 = sb[o_ + ro1]; g11 = sb[o_ + ro1 + 1]; g12 = sb[o_ + ro1 + 2];       \
    g20 = sb[o_ + ro2]; g21 = sb[o_ + ro2 + 1]; g22 = sb[o_ + ro2 + 2];       \
} while (0)

#define PREFETCH_M(P) do {                                                    \
    const int pc_ = (P) < 0 ? 0 : ((P) > ND - 1 ? ND - 1 : (P));              \
    const float pm_ = ((P) >= 0 && (P) < ND) ? 1.f : 0.f;                     \
    const int o_ = pc_ * PLI;                                                 \
    g00 = sb[o_ + ro0] * pm_; g01 = sb[o_ + ro0 + 1] * pm_; g02 = sb[o_ + ro0 + 2] * pm_; \
    g10 = sb[o_ + ro1] * pm_; g11 = sb[o_ + ro1 + 1] * pm_; g12 = sb[o_ + ro1 + 2] * pm_; \
    g20 = sb[o_ + ro2] * pm_; g21 = sb[o_ + ro2 + 1] * pm_; g22 = sb[o_ + ro2 + 2] * pm_; \
} while (0)

#define STAGE_WRITE() do {                                                    \
    ldw[0] = g00; ldw[1] = g01; ldw[2] = g02;                                 \
    ldw[LDSW + 0] = g10; ldw[LDSW + 1] = g11; ldw[LDSW + 2] = g12;            \
    ldw[2 * LDSW + 0] = g20; ldw[2 * LDSW + 1] = g21; ldw[2 * LDSW + 2] = g22;\
} while (0)

// one h-row pass of tensor T into slot SP; packed (j0,j1) + scalar j2
#define ROWPASS(T, SP, RR) do {                                               \
    const float* rp_ = RPTR(T, RR);                                           \
    const float xm_ = rp_[-1], x0_ = rp_[0], x1_ = rp_[1], x2_ = rp_[2], xp_ = rp_[3]; \
    const v2f L_ = mk2(xm_, x0_), M_ = mk2(x0_, x1_), R_ = mk2(x1_, x2_);     \
    const v2f   sA_ = (L_ + R_ + 2.f * M_) * 0.25f;                           \
    const float s2_ = (x1_ + xp_ + 2.f * x2_) * 0.25f;                        \
    const v2f   tA_ = R_ - L_;                                                \
    const float t2_ = xp_ - x1_;                                              \
    if ((RR) == 0) {                                                          \
        qa[T][SP][0] = 0.25f * sA_;  qc[T][SP][0] = 0.25f * s2_;              \
        qa[T][SP][1] = -sA_;         qc[T][SP][1] = -s2_;                     \
        qa[T][SP][2] = 0.25f * tA_;  qc[T][SP][2] = 0.25f * t2_;              \
    } else if ((RR) == 1) {                                                   \
        qa[T][SP][0] += 0.5f * sA_;  qc[T][SP][0] += 0.5f * s2_;              \
        /* sobel_h center weight = 0 -> ts unchanged */                       \
        qa[T][SP][2] += 0.5f * tA_;  qc[T][SP][2] += 0.5f * t2_;              \
    } else {                                                                  \
        qa[T][SP][0] += 0.25f * sA_; qc[T][SP][0] += 0.25f * s2_;             \
        qa[T][SP][1] += sA_;         qc[T][SP][1] += s2_;                     \
        qa[T][SP][2] += 0.25f * tA_; qc[T][SP][2] += 0.25f * t2_;             \
    }                                                                         \
} while (0)

#define PROCESS(SP, PNEXT) do {                                               \
    __syncthreads();                                                          \
    STAGE_WRITE();                                                            \
    __syncthreads();                                                          \
    PREFETCH(PNEXT);                                                          \
    ROWPASS(0, SP, 0); ROWPASS(0, SP, 1); ROWPASS(0, SP, 2);                  \
    ROWPASS(1, SP, 0); ROWPASS(1, SP, 1); ROWPASS(1, SP, 2);                  \
} while (0)

#define PROCESS_M(SP, PNEXT) do {                                             \
    __syncthreads();                                                          \
    STAGE_WRITE();                                                            \
    __syncthreads();                                                          \
    PREFETCH_M(PNEXT);                                                        \
    ROWPASS(0, SP, 0); ROWPASS(0, SP, 1); ROWPASS(0, SP, 2);                  \
    ROWPASS(1, SP, 0); ROWPASS(1, SP, 1); ROWPASS(1, SP, 2);                  \
} while (0)

#define PROCESS_LAST(SP) do {                                                 \
    __syncthreads();                                                          \
    STAGE_WRITE();                                                            \
    __syncthreads();                                                          \
    ROWPASS(0, SP, 0); ROWPASS(0, SP, 1); ROWPASS(0, SP, 2);                  \
    ROWPASS(1, SP, 0); ROWPASS(1, SP, 1); ROWPASS(1, SP, 2);                  \
} while (0)

#define EDGEPK(T, SM, SC, SP, EA, E2) do {                                    \
    const v2f   gxA_ = (qa[T][SM][2] + qa[T][SP][2] + 2.f * qa[T][SC][2]) * 0.25f; \
    const float gx2_ = (qc[T][SM][2] + qc[T][SP][2] + 2.f * qc[T][SC][2]) * 0.25f; \
    const v2f   gyA_ = (qa[T][SM][1] + qa[T][SP][1] + 2.f * qa[T][SC][1]) * 0.25f; \
    const float gy2_ = (qc[T][SM][1] + qc[T][SP][1] + 2.f * qc[T][SC][1]) * 0.25f; \
    const v2f   gzA_ = qa[T][SP][0] - qa[T][SM][0];                           \
    const float gz2_ = qc[T][SP][0] - qc[T][SM][0];                           \
    const v2f   dA_ = gxA_ * gxA_ + gyA_ * gyA_ + gzA_ * gzA_ + 1e-8f;        \
    const float d2_ = gx2_ * gx2_ + gy2_ * gy2_ + gz2_ * gz2_ + 1e-8f;        \
    EA = mk2(sqrtf(dA_.x), sqrtf(dA_.y));                                     \
    E2 = sqrtf(d2_);                                                          \
} while (0)

#define EMIT(SM, SC, SP) do {                                                 \
    v2f eA0_, eA1_; float e20_, e21_;                                         \
    EDGEPK(0, SM, SC, SP, eA0_, e20_);                                        \
    EDGEPK(1, SM, SC, SP, eA1_, e21_);                                        \
    const v2f dfA_ = eA0_ - eA1_;                                             \
    accA += mk2(fabsf(dfA_.x), fabsf(dfA_.y));                                \
    acc2 += fabsf(e20_ - e21_);                                               \
} while (0)

    // 18 phases: plane P_k = d0-1+k, slot = k%3; emit outputs from k>=2
    PREFETCH_M(d0 - 1);
    PROCESS(0, d0);           // k=0: computes plane d0-1
    PROCESS(1, d0 + 1);       // k=1
    for (int gg = 0; gg < 4; ++gg) {          // k=2..13
        const int p = d0 + 1 + gg * 3;
        PROCESS(2, p + 1); EMIT(0, 1, 2);
        PROCESS(0, p + 2); EMIT(1, 2, 0);
        PROCESS(1, p + 3); EMIT(2, 0, 1);
    }
    PROCESS(2, d0 + 14);   EMIT(0, 1, 2);     // k=14
    PROCESS(0, d0 + 15);   EMIT(1, 2, 0);     // k=15
    PROCESS_M(1, d0 + 16); EMIT(2, 0, 1);     // k=16 (prefetch may be OOB plane)
    PROCESS_LAST(2);       EMIT(0, 1, 2);     // k=17: computes plane d0+16

#undef RPTR
#undef PREFETCH
#undef PREFETCH_M
#undef STAGE_WRITE
#undef ROWPASS
#undef PROCESS
#undef PROCESS_M
#undef PROCESS_LAST
#undef EDGEPK
#undef EMIT

    // wave reduce -> block reduce -> one atomic per block
    float acc = accA.x + accA.y + acc2;
    #pragma unroll
    for (int off = 32; off > 0; off >>= 1)
        acc += __shfl_down(acc, off, 64);
    if (lane == 0) wsum[wid] = acc;
    __syncthreads();
    if (threadIdx.x == 0) {
        const float invN = 1.f / (float)((long long)NB * ND * NH * NW);
        atomicAdd(out, (wsum[0] + wsum[1] + wsum[2] + wsum[3]) * invN);
    }
}

} // namespace

extern "C" void kernel_launch(void* const* d_in, const int* in_sizes, int n_in,
                              void* d_out, int out_size, void* d_ws, size_t ws_size,
                              hipStream_t stream) {
    const float* pred = (const float*)d_in[0];
    const float* targ = (const float*)d_in[1];
    float* out = (float*)d_out;
    (void)in_sizes; (void)n_in; (void)out_size; (void)d_ws; (void)ws_size;

    hipMemsetAsync(out, 0, sizeof(float), stream);

    dim3 grid(ND / CD, NH / 4, NB);   // (8, 48, 4) = 1536 blocks, 6/CU
    dim3 block(256);
    edge_loss3d<<<grid, block, 0, stream>>>(pred, targ, out);
}